// Round 6
// baseline (31.366 us; speedup 1.0000x reference)
//
#include <hip/hip_runtime.h>
#include <hip/hip_bf16.h>

// DCN cross stack collapsed (validated rounds 1-5):
//   u_k = x0.w_k, e_k = d_k.w_k (d_k = sum_{j<k} b_j), c_{k+1} = c_k(1+u_k)+e_k
//   out[t] = c_4 * (x0 . Wout[:,t]) + d_4.Wout[:,t] + bo[t]
// 12 dots/row == GEMM X[65536x512] @ Wcat[512x12pad16] via mfma_f32_16x16x32_bf16.
//
// Round-6: two-kernel split. Kernel 1 (tiny) precomputes the block-invariant
// B-fragment table (bf16) + fp32 constants into d_ws. Kernel 2 holds the B
// table in REGISTERS (64 VGPR), constants in SGPRs -> no LDS table, no
// syncthreads, no per-block rebuild; pure x stream with depth-3 register
// prefetch and split-x 2-term MFMA (x at ~16-bit precision, B at bf16).

typedef float v4f __attribute__((ext_vector_type(4)));
typedef float f32x4 __attribute__((ext_vector_type(4)));
typedef short s16x8 __attribute__((ext_vector_type(8)));

__device__ __forceinline__ short f2bf(float v) {          // RTNE fp32->bf16
  return __builtin_bit_cast(short, __float2bfloat16(v));
}
__device__ __forceinline__ float bf2f(short s) {
  return __uint_as_float(((unsigned)(unsigned short)s) << 16);
}

template<int CTRL>
__device__ __forceinline__ float dpp_add(float v) {
  int t = __builtin_amdgcn_update_dpp(0, __float_as_int(v), CTRL, 0xF, 0xF, true);
  return v + __int_as_float(t);
}
__device__ __forceinline__ float wave_reduce(float v) {   // total in lane 63
  v = dpp_add<0x111>(v); v = dpp_add<0x112>(v); v = dpp_add<0x114>(v);
  v = dpp_add<0x118>(v); v = dpp_add<0x142>(v); v = dpp_add<0x143>(v);
  return v;
}

// ---- kernel 1: build B-fragment table + constants into ws ------------------
// ws layout: [0,16384): s16x8 Bh[16][64];  [16384,+48): float egs[12]
__global__ __launch_bounds__(64) void build_tab(
    const float* __restrict__ cw, const float* __restrict__ cb,
    const float* __restrict__ Wo, const float* __restrict__ bo, void* ws)
{
  s16x8* Bt = (s16x8*)ws;
  float* egs = (float*)((char*)ws + 16384);
  const int s = blockIdx.x, l = threadIdx.x;
  const int c = l & 15, k0 = s * 32 + ((l >> 4) << 3);

  float f[8];
  if (c < 4) {
    v4f a = *(const v4f*)(cw + c * 512 + k0);
    v4f b = *(const v4f*)(cw + c * 512 + k0 + 4);
    #pragma unroll
    for (int j = 0; j < 4; ++j) { f[j] = a[j]; f[4 + j] = b[j]; }
  } else if (c < 12) {
    #pragma unroll
    for (int j = 0; j < 8; ++j) f[j] = Wo[(k0 + j) * 8 + (c - 4)];
  } else {
    #pragma unroll
    for (int j = 0; j < 8; ++j) f[j] = 0.f;
  }
  s16x8 h;
  #pragma unroll
  for (int j = 0; j < 8; ++j) h[j] = f2bf(f[j]);
  Bt[s * 64 + l] = h;

  if (s == 0) {  // block 0's single wave: exact fp32 constants
    const int f0 = l << 3;
    v4f d0a = *(const v4f*)(cb + f0),        d0b = *(const v4f*)(cb + f0 + 4);
    v4f c1a = *(const v4f*)(cb + 512 + f0),  c1b = *(const v4f*)(cb + 512 + f0 + 4);
    v4f c2a = *(const v4f*)(cb + 1024 + f0), c2b = *(const v4f*)(cb + 1024 + f0 + 4);
    v4f c3a = *(const v4f*)(cb + 1536 + f0), c3b = *(const v4f*)(cb + 1536 + f0 + 4);
    v4f w1a = *(const v4f*)(cw + 512 + f0),  w1b = *(const v4f*)(cw + 512 + f0 + 4);
    v4f w2a = *(const v4f*)(cw + 1024 + f0), w2b = *(const v4f*)(cw + 1024 + f0 + 4);
    v4f w3a = *(const v4f*)(cw + 1536 + f0), w3b = *(const v4f*)(cw + 1536 + f0 + 4);
    float e1p = 0.f, e2p = 0.f, e3p = 0.f;
    v4f dA = d0a, dB = d0b;
    #pragma unroll
    for (int e = 0; e < 4; ++e) e1p += dA[e] * w1a[e] + dB[e] * w1b[e];
    dA += c1a; dB += c1b;
    #pragma unroll
    for (int e = 0; e < 4; ++e) e2p += dA[e] * w2a[e] + dB[e] * w2b[e];
    dA += c2a; dB += c2b;
    #pragma unroll
    for (int e = 0; e < 4; ++e) e3p += dA[e] * w3a[e] + dB[e] * w3b[e];
    dA += c3a; dB += c3b;
    float gp[8] = {0.f,0.f,0.f,0.f,0.f,0.f,0.f,0.f};
    #pragma unroll
    for (int e = 0; e < 4; ++e) {
      const float* wra = Wo + (f0 + e) * 8;
      const float* wrb = Wo + (f0 + 4 + e) * 8;
      #pragma unroll
      for (int t = 0; t < 8; ++t) gp[t] += dA[e] * wra[t] + dB[e] * wrb[t];
    }
    e1p = wave_reduce(e1p); e2p = wave_reduce(e2p); e3p = wave_reduce(e3p);
    #pragma unroll
    for (int t = 0; t < 8; ++t) gp[t] = wave_reduce(gp[t]);
    if (l == 63) {
      egs[0] = e1p; egs[1] = e2p; egs[2] = e3p;
      #pragma unroll
      for (int t = 0; t < 8; ++t) egs[3 + t] = gp[t] + bo[t];
    }
  }
}

// ---- kernel 2: pure x stream, B table in registers -------------------------
__global__ __launch_bounds__(256, 4) void cross_stream(
    const float* __restrict__ x, const void* __restrict__ ws,
    float* __restrict__ out)
{
  __shared__ float ct[4][16][17];  // epilogue transpose only (4.25 KB)

  const int tid = threadIdx.x, lane = tid & 63, wv = tid >> 6;
  const s16x8* Bt = (const s16x8*)ws;
  const float* egs = (const float*)((const char*)ws + 16384);

  // B fragments -> 64 VGPRs (16 coalesced dwordx4, L2/L3-resident)
  s16x8 Bf[16];
  #pragma unroll
  for (int s = 0; s < 16; ++s) Bf[s] = Bt[s * 64 + lane];

  // constants: uniform address -> scalar loads
  const float e1 = egs[0], e2 = egs[1], e3 = egs[2];
  float gg[8];
  #pragma unroll
  for (int t = 0; t < 8; ++t) gg[t] = egs[3 + t];

  const int row0 = (blockIdx.x << 6) + (wv << 4);
  const float* xr = x + (size_t)(row0 + (lane & 15)) * 512 + ((lane >> 4) << 3);

  f32x4 acc = {0.f, 0.f, 0.f, 0.f};
  v4f xa[3], xb[3];
  #pragma unroll
  for (int p = 0; p < 3; ++p) {
    xa[p] = *(const v4f*)(xr + p * 32);
    xb[p] = *(const v4f*)(xr + p * 32 + 4);
  }
  #pragma unroll
  for (int s = 0; s < 16; ++s) {
    const int cur = s % 3;
    const v4f pa = xa[cur], pb = xb[cur];
    if (s + 3 < 16) {
      xa[cur] = *(const v4f*)(xr + (s + 3) * 32);
      xb[cur] = *(const v4f*)(xr + (s + 3) * 32 + 4);
    }
    s16x8 ah, al;
    #pragma unroll
    for (int j = 0; j < 4; ++j) {
      ah[j]     = f2bf(pa[j]); al[j]     = f2bf(pa[j] - bf2f(ah[j]));
      ah[4 + j] = f2bf(pb[j]); al[4 + j] = f2bf(pb[j] - bf2f(ah[4 + j]));
    }
    acc = __builtin_amdgcn_mfma_f32_16x16x32_bf16(ah, Bf[s], acc, 0, 0, 0);
    acc = __builtin_amdgcn_mfma_f32_16x16x32_bf16(al, Bf[s], acc, 0, 0, 0);
  }

  // epilogue: transpose C via wave-private LDS, recurrence, store
  #pragma unroll
  for (int j = 0; j < 4; ++j)
    ct[wv][((lane >> 4) << 2) + j][lane & 15] = acc[j];
  __builtin_amdgcn_s_waitcnt(0);  // lgkm drain within wave (wave-private tile)
  if (lane < 16) {
    const float u0 = ct[wv][lane][0], u1 = ct[wv][lane][1];
    const float u2 = ct[wv][lane][2], u3 = ct[wv][lane][3];
    const float cc1 = 1.f + u0;
    const float cc2 = fmaf(cc1, u1, cc1) + e1;
    const float cc3 = fmaf(cc2, u2, cc2) + e2;
    const float cc4 = fmaf(cc3, u3, cc3) + e3;
    v4f o0, o1;
    #pragma unroll
    for (int t = 0; t < 4; ++t) {
      o0[t] = fmaf(cc4, ct[wv][lane][4 + t], gg[t]);
      o1[t] = fmaf(cc4, ct[wv][lane][8 + t], gg[4 + t]);
    }
    float* op = out + (size_t)(row0 + lane) * 8;
    *(v4f*)(op)     = o0;
    *(v4f*)(op + 4) = o1;
  }
}

extern "C" void kernel_launch(void* const* d_in, const int* in_sizes, int n_in,
                              void* d_out, int out_size, void* d_ws, size_t ws_size,
                              hipStream_t stream) {
  const float* x  = (const float*)d_in[0];
  const float* cw = (const float*)d_in[1];
  const float* cb = (const float*)d_in[2];
  const float* Wo = (const float*)d_in[3];
  const float* bo = (const float*)d_in[4];
  float* out = (float*)d_out;
  const int B = in_sizes[0] / 512;          // 65536
  hipLaunchKernelGGL(build_tab, dim3(16), dim3(64), 0, stream,
                     cw, cb, Wo, bo, d_ws);
  hipLaunchKernelGGL(cross_stream, dim3(B >> 6), dim3(256), 0, stream,
                     x, d_ws, out);
}